// Round 6
// baseline (3062.574 us; speedup 1.0000x reference)
//
#include <hip/hip_runtime.h>
#include <hip/hip_bf16.h>
#include <hip/hip_fp16.h>

// GraphPrefixLLMCaptioner forward, MI355X.
// B=32 T=128 R=16 A=4 C=6 D=256 H=256 V=32000, GRAPH_STEPS=1, PRIOR_W=1.
// Structure:
//   1) small f32 kernels for the graph phase + decode-invariant precomputes
//   2) k_decode: 32 blocks (one per batch row), Whh held as packed fp16 in VGPRs,
//      sequential 128-step GRU with fused attention/concept gating
//   3) k_gemm: [4096,256]x[256,32000] logits projection via fp16 MFMA (f32 accum)
// Round 5: identical resubmission (6 rounds, zero HW signal; holding for attribution).

#define DEV __device__ __forceinline__

typedef float    f32x4v  __attribute__((ext_vector_type(4)));
typedef _Float16 f16x8   __attribute__((ext_vector_type(8)));
typedef _Float16 h2v     __attribute__((ext_vector_type(2)));

DEV ushort f2h(float f) {
  _Float16 h = (_Float16)f;
  union { _Float16 h; ushort s; } c; c.h = h; return c.s;
}

DEV float fdot2(unsigned int w, unsigned int h, float acc) {
  union { unsigned int u; h2v v; } a, b; a.u = w; b.u = h;
#if __has_builtin(__builtin_amdgcn_fdot2)
  return __builtin_amdgcn_fdot2(a.v, b.v, acc, false);
#else
  return acc + (float)a.v.x * (float)b.v.x + (float)a.v.y * (float)b.v.y;
#endif
}

// ---------------------------------------------------------------------------
// Generic: out[M,N] = act(A[M,256] @ W[256,N](ldw) + bias + res[(row%resMod),N])
// optional row gather on A. Block=256 threads, 16 rows per block.
// ---------------------------------------------------------------------------
__global__ __launch_bounds__(256) void k_t1(
    const float* __restrict__ A, const int* __restrict__ gather, int M,
    const float* __restrict__ W, int ldw, int N,
    const float* __restrict__ bias, const float* __restrict__ res, int resMod,
    int do_gelu, float* __restrict__ out)
{
  __shared__ float As[16][256];
  const int tid = threadIdx.x;
  const int m0 = blockIdx.x * 16;
  #pragma unroll
  for (int p = 0; p < 16; ++p) {
    int row = m0 + p;
    float v = 0.f;
    if (row < M) {
      int ar = gather ? gather[row] : row;
      v = A[(size_t)ar * 256 + tid];
    }
    As[p][tid] = v;
  }
  __syncthreads();
  for (int nb = 0; nb < N; nb += 256) {
    const int col = nb + tid;
    float acc[16];
    const float bz = bias ? bias[col] : 0.f;
    #pragma unroll
    for (int r = 0; r < 16; ++r) acc[r] = 0.f;
    const float* Wp = W + col;
    for (int k = 0; k < 256; k += 4) {
      float w0 = Wp[(size_t)(k + 0) * ldw];
      float w1 = Wp[(size_t)(k + 1) * ldw];
      float w2 = Wp[(size_t)(k + 2) * ldw];
      float w3 = Wp[(size_t)(k + 3) * ldw];
      #pragma unroll
      for (int r = 0; r < 16; ++r) {
        const float4 a = *(const float4*)&As[r][k];
        acc[r] = fmaf(a.x, w0, acc[r]);
        acc[r] = fmaf(a.y, w1, acc[r]);
        acc[r] = fmaf(a.z, w2, acc[r]);
        acc[r] = fmaf(a.w, w3, acc[r]);
      }
    }
    const int rows = min(16, M - m0);
    for (int r = 0; r < rows; ++r) {
      float v = acc[r] + bz;
      if (res) v += res[((m0 + r) % resMod) * N + col];
      if (do_gelu) v = 0.5f * v * (1.f + erff(v * 0.70710678118654752f));
      out[(size_t)(m0 + r) * N + col] = v;
    }
  }
}

// ---------------------------------------------------------------------------
// out[M,256] = A[M,256] @ W[256,256]^T   (W row-major [h][d], dot over d)
// ---------------------------------------------------------------------------
__global__ __launch_bounds__(256) void k_t2(
    const float* __restrict__ A, int M, const float* __restrict__ W,
    float* __restrict__ out)
{
  __shared__ float As[16][256];
  __shared__ float Wt[32][257];
  const int tid = threadIdx.x;
  const int m0 = blockIdx.x * 16;
  #pragma unroll
  for (int p = 0; p < 16; ++p) {
    int row = m0 + p;
    As[p][tid] = (row < M) ? A[(size_t)row * 256 + tid] : 0.f;
  }
  float acc[16];
  #pragma unroll
  for (int r = 0; r < 16; ++r) acc[r] = 0.f;
  for (int d0 = 0; d0 < 256; d0 += 32) {
    __syncthreads();
    #pragma unroll
    for (int p = 0; p < 32; ++p) {
      int e = p * 256 + tid;
      int hh = e >> 5, dd = e & 31;
      Wt[dd][hh] = W[hh * 256 + d0 + dd];
    }
    __syncthreads();
    #pragma unroll
    for (int dd = 0; dd < 32; dd += 4) {
      float w0 = Wt[dd + 0][tid], w1 = Wt[dd + 1][tid];
      float w2 = Wt[dd + 2][tid], w3 = Wt[dd + 3][tid];
      #pragma unroll
      for (int r = 0; r < 16; ++r) {
        const float4 a = *(const float4*)&As[r][d0 + dd];
        acc[r] = fmaf(a.x, w0, fmaf(a.y, w1, fmaf(a.z, w2, fmaf(a.w, w3, acc[r]))));
      }
    }
  }
  const int rows = min(16, M - m0);
  for (int r = 0; r < rows; ++r) out[(size_t)(m0 + r) * 256 + tid] = acc[r];
}

// ---------------------------------------------------------------------------
// region->anatomy edges + a_mid = (ra^T @ RF)/R    one block per batch
// ---------------------------------------------------------------------------
__global__ __launch_bounds__(256) void k_graph_ra(
    const float* __restrict__ rp, const float* __restrict__ aw0,
    const float* __restrict__ RF, const float* __restrict__ region_prior,
    float* __restrict__ a_mid)
{
  const int b = blockIdx.x, tid = threadIdx.x;
  __shared__ float s_rp[16 * 256];
  __shared__ float s_rf[16 * 256];
  __shared__ float s_aw[4 * 256];
  __shared__ float s_ra[64];
  for (int i = tid; i < 4096; i += 256) { s_rp[i] = rp[b * 4096 + i]; s_rf[i] = RF[b * 4096 + i]; }
  for (int i = tid; i < 1024; i += 256) s_aw[i] = aw0[i];
  __syncthreads();
  if (tid < 64) {
    const int r = tid >> 2, aa = tid & 3;
    float s = 0.f;
    const float4* x4 = (const float4*)(s_rp + r * 256);
    const float4* w4 = (const float4*)(s_aw + aa * 256);
    for (int k = 0; k < 64; ++k) {
      float4 x = x4[k], ww = w4[k];
      s += x.x * ww.x + x.y * ww.y + x.z * ww.z + x.w * ww.w;
    }
    s = s * 0.0625f + logf(fmaxf(region_prior[r * 4 + aa], 1e-8f));
    float m = s;
    m = fmaxf(m, __shfl_xor(m, 1)); m = fmaxf(m, __shfl_xor(m, 2));
    float e = __expf(s - m);
    float sum = e;
    sum += __shfl_xor(sum, 1); sum += __shfl_xor(sum, 2);
    s_ra[r * 4 + aa] = e / sum;
  }
  __syncthreads();
  const int d = tid;
  #pragma unroll
  for (int aa = 0; aa < 4; ++aa) {
    float acc = 0.f;
    #pragma unroll
    for (int r = 0; r < 16; ++r) acc += s_ra[r * 4 + aa] * s_rf[r * 256 + d];
    a_mid[((b * 4) + aa) * 256 + d] = acc * (1.f / 16.f);
  }
}

// ---------------------------------------------------------------------------
// anatomy->concept edges + c_mid = (ac^T @ a)/A    one block per batch
// ---------------------------------------------------------------------------
__global__ __launch_bounds__(256) void k_graph_ac(
    const float* __restrict__ aW, const float* __restrict__ cw0,
    const float* __restrict__ a_new, const float* __restrict__ concept_prior,
    float* __restrict__ c_mid)
{
  const int b = blockIdx.x, tid = threadIdx.x;
  __shared__ float s_aw[4 * 256], s_cw[6 * 256], s_an[4 * 256];
  __shared__ float s_sc[24], s_ac[24];
  for (int i = tid; i < 1024; i += 256) { s_aw[i] = aW[b * 1024 + i]; s_an[i] = a_new[b * 1024 + i]; }
  for (int i = tid; i < 1536; i += 256) s_cw[i] = cw0[i];
  __syncthreads();
  if (tid < 24) {
    const int aa = tid / 6, cc = tid % 6;
    float s = 0.f;
    const float4* x4 = (const float4*)(s_aw + aa * 256);
    const float4* w4 = (const float4*)(s_cw + cc * 256);
    for (int k = 0; k < 64; ++k) {
      float4 x = x4[k], ww = w4[k];
      s += x.x * ww.x + x.y * ww.y + x.z * ww.z + x.w * ww.w;
    }
    s_sc[aa * 6 + cc] = s * 0.0625f + logf(fmaxf(concept_prior[aa * 6 + cc], 1e-8f));
  }
  __syncthreads();
  if (tid < 4) {
    const int aa = tid;
    float m = -1e30f;
    for (int cc = 0; cc < 6; ++cc) m = fmaxf(m, s_sc[aa * 6 + cc]);
    float e[6]; float sum = 0.f;
    for (int cc = 0; cc < 6; ++cc) { e[cc] = __expf(s_sc[aa * 6 + cc] - m); sum += e[cc]; }
    for (int cc = 0; cc < 6; ++cc) s_ac[aa * 6 + cc] = e[cc] / sum;
  }
  __syncthreads();
  const int d = tid;
  #pragma unroll
  for (int cc = 0; cc < 6; ++cc) {
    float acc = 0.f;
    #pragma unroll
    for (int aa = 0; aa < 4; ++aa) acc += s_ac[aa * 6 + cc] * s_an[aa * 256 + d];
    c_mid[((b * 6) + cc) * 256 + d] = acc * 0.25f;
  }
}

__global__ void k_mean(const float* __restrict__ RF, float* __restrict__ outm)
{
  const int b = blockIdx.x, d = threadIdx.x;
  float s = 0.f;
  #pragma unroll
  for (int r = 0; r < 16; ++r) s += RF[(b * 16 + r) * 256 + d];
  outm[b * 256 + d] = s * (1.f / 16.f);
}

// t_r[row<512] = bhg . r_p[row] ; t_c[row-512] = bhg . c_p[row-512]
__global__ void k_tvec(const float* __restrict__ rp, const float* __restrict__ cp,
                       const float* __restrict__ bhg,
                       float* __restrict__ tr, float* __restrict__ tc)
{
  const int row = blockIdx.x;
  const int lane = threadIdx.x;  // 64
  const float* src = (row < 512) ? (rp + row * 256) : (cp + (row - 512) * 256);
  float p = 0.f;
  #pragma unroll
  for (int i = 0; i < 4; ++i) p += src[lane * 4 + i] * bhg[lane * 4 + i];
  p += __shfl_xor(p, 1);  p += __shfl_xor(p, 2);  p += __shfl_xor(p, 4);
  p += __shfl_xor(p, 8);  p += __shfl_xor(p, 16); p += __shfl_xor(p, 32);
  if (lane == 0) { if (row < 512) tr[row] = p; else tc[row - 512] = p; }
}

// Whh[256,768] f32 -> packed fp16 pairs Wp[i][g] = (h=2i, h=2i+1)
__global__ void k_packwhh(const float* __restrict__ Whh, unsigned int* __restrict__ Wp)
{
  int idx = blockIdx.x * 256 + threadIdx.x;  // < 98304
  int i = idx / 768, g = idx % 768;
  ushort lo = f2h(Whh[(2 * i) * 768 + g]);
  ushort hi = f2h(Whh[(2 * i + 1) * 768 + g]);
  Wp[idx] = ((unsigned int)hi << 16) | lo;
}

// Wout[256,32000] f32 -> Bt[32000][256] fp16 (transposed, n-major)
__global__ void k_packwt(const float* __restrict__ Wout, ushort* __restrict__ Bt)
{
  __shared__ float tile[64][33];
  const int tid = threadIdx.x;
  const int n0 = blockIdx.x * 32, k0 = blockIdx.y * 64;
  #pragma unroll
  for (int p = 0; p < 8; ++p) {
    int e = p * 256 + tid;
    int kk = e >> 5, nn = e & 31;
    tile[kk][nn] = Wout[(size_t)(k0 + kk) * 32000 + n0 + nn];
  }
  __syncthreads();
  #pragma unroll
  for (int p = 0; p < 8; ++p) {
    int e = p * 256 + tid;
    int nn = e >> 6, kk = e & 63;
    Bt[(size_t)(n0 + nn) * 256 + k0 + kk] = f2h(tile[kk][nn]);
  }
}

// ---------------------------------------------------------------------------
// Sequential decode. One block per batch row, 512 threads (8 waves).
// Thread t owns gate column t (r-gate t<256, z-gate t>=256) with full 256-h
// fp16 weight column in 128 VGPRs, plus a HALF (by hf=t>>8) of n-gate column
// 512+(t&255) in 64 VGPRs. h broadcast via packed-fp16 LDS.
// attn/tc weights are read straight from LDS (broadcast) to stay <256 VGPRs.
// NOTE: __launch_bounds__(512,2) is REQUIRED: 8 waves need 2 waves/SIMD, so
// VGPR must be capped at 256 or the block cannot launch.
// ---------------------------------------------------------------------------
__global__ __launch_bounds__(512, 2) void k_decode(
    const float* __restrict__ RFih, const float* __restrict__ Cih,
    const float* __restrict__ Pr, const float* __restrict__ Pc,
    const float* __restrict__ tr, const float* __restrict__ tcb,
    const float* __restrict__ bhh, const unsigned int* __restrict__ Wpack,
    const float* __restrict__ X, const float* __restrict__ h0,
    ushort* __restrict__ Ah)
{
  const int b = blockIdx.x;
  const int tid = threadIdx.x;

  __shared__ float s_pr[16 * 260];
  __shared__ float s_pc[6 * 260];
  __shared__ float s_rfnT[256 * 20];
  __shared__ float s_cinT[256 * 12];
  __shared__ float s_bhh[768];
  __shared__ float s_tr[16];
  __shared__ float s_tc[8];
  __shared__ __align__(16) float s_h[256];
  __shared__ __align__(16) unsigned int s_hp[128];
  __shared__ __align__(16) float s_attn[16];
  __shared__ __align__(16) float s_tcw[8];
  __shared__ float s_srq[16];
  __shared__ float s_scq[8];
  __shared__ float s_z[256];
  __shared__ float s_gin[256];
  __shared__ float s_pn[512];

  // ---- preload LDS ----
  for (int i = tid; i < 16 * 256; i += 512) {
    int r = i >> 8, h = i & 255;
    s_pr[r * 260 + h] = Pr[(b * 16 + r) * 256 + h];
  }
  for (int i = tid; i < 6 * 256; i += 512) {
    int c = i >> 8, h = i & 255;
    s_pc[c * 260 + h] = Pc[(b * 6 + c) * 256 + h];
  }
  for (int i = tid; i < 256 * 16; i += 512) {
    int gn = i & 255, r = i >> 8;
    s_rfnT[gn * 20 + r] = RFih[(b * 16 + r) * 768 + 512 + gn];
  }
  for (int i = tid; i < 256 * 6; i += 512) {
    int gn = i & 255, c = i >> 8;
    s_cinT[gn * 12 + c] = Cih[(b * 6 + c) * 768 + 512 + gn];
  }
  for (int i = tid; i < 768; i += 512) s_bhh[i] = bhh[i];
  if (tid < 16) s_tr[tid] = tr[b * 16 + tid];
  if (tid < 8)  s_tc[tid] = (tid < 6) ? tcb[b * 6 + tid] : 0.f;
  if (tid < 256) {
    float v = h0[b * 256 + tid];
    s_h[tid] = v;
    ((ushort*)s_hp)[tid] = f2h(v);
  }

  // ---- step-invariant registers ----
  float rf_own[16], ci_own[6];
  #pragma unroll
  for (int r = 0; r < 16; ++r) rf_own[r] = RFih[(b * 16 + r) * 768 + tid];
  #pragma unroll
  for (int c = 0; c < 6; ++c) ci_own[c] = Cih[(b * 6 + c) * 768 + tid];
  const float bhh_own = bhh[tid];

  unsigned int wA[128];
  #pragma unroll
  for (int i = 0; i < 128; ++i) wA[i] = Wpack[i * 768 + tid];
  const int hf = tid >> 8;  // wave-uniform: 0 for waves 0-3, 1 for waves 4-7
  const int ncol = 512 + (tid & 255);
  unsigned int wN[64];
  #pragma unroll
  for (int i = 0; i < 64; ++i) wN[i] = Wpack[(hf * 64 + i) * 768 + ncol];

  __syncthreads();

  const float scale = 0.0625f;
  const float* Xb = X + (size_t)b * 128 * 768;

  for (int t = 0; t < 128; ++t) {
    // ---- phase 1: raw attention / concept scores (linear in h) ----
    if (tid < 256) {
      const int r = tid >> 4, j = tid & 15;
      const float4* pr4 = (const float4*)(s_pr + r * 260 + j * 16);
      const float4* h4  = (const float4*)(s_h + j * 16);
      float p = 0.f;
      #pragma unroll
      for (int k = 0; k < 4; ++k) {
        float4 a = pr4[k], hh = h4[k];
        p += a.x * hh.x + a.y * hh.y + a.z * hh.z + a.w * hh.w;
      }
      p += __shfl_xor(p, 1); p += __shfl_xor(p, 2);
      p += __shfl_xor(p, 4); p += __shfl_xor(p, 8);
      if (j == 0) s_srq[r] = p + s_tr[r];
    } else if (tid < 448) {
      const int q = tid - 256;
      const int c = q >> 5, j = q & 31;
      const float4* pc4 = (const float4*)(s_pc + c * 260 + j * 8);
      const float4* h4  = (const float4*)(s_h + j * 8);
      float p = 0.f;
      #pragma unroll
      for (int k = 0; k < 2; ++k) {
        float4 a = pc4[k], hh = h4[k];
        p += a.x * hh.x + a.y * hh.y + a.z * hh.z + a.w * hh.w;
      }
      p += __shfl_xor(p, 1); p += __shfl_xor(p, 2); p += __shfl_xor(p, 4);
      p += __shfl_xor(p, 8); p += __shfl_xor(p, 16);
      if (j == 0) s_scq[c] = p + s_tc[c];
    }
    __syncthreads();
    // ---- phase 2: softmax over regions; sigmoid-normalize over concepts ----
    if (tid < 16) {
      float s = s_srq[tid] * scale;
      float m = s;
      m = fmaxf(m, __shfl_xor(m, 1)); m = fmaxf(m, __shfl_xor(m, 2));
      m = fmaxf(m, __shfl_xor(m, 4)); m = fmaxf(m, __shfl_xor(m, 8));
      float e = __expf(s - m);
      float sum = e;
      sum += __shfl_xor(sum, 1); sum += __shfl_xor(sum, 2);
      sum += __shfl_xor(sum, 4); sum += __shfl_xor(sum, 8);
      s_attn[tid] = e / sum;
    } else if (tid >= 32 && tid < 40) {
      const int c = tid - 32;
      float v = (c < 6) ? 1.f / (1.f + __expf(-s_scq[c])) : 0.f;
      float sum = v;
      sum += __shfl_xor(sum, 1); sum += __shfl_xor(sum, 2); sum += __shfl_xor(sum, 4);
      s_tcw[c] = v / fmaxf(sum, 1e-8f);
    }
    __syncthreads();
    // ---- phase 3: gi (input gates) and gh (hidden gates) ----
    const float* Xrow = Xb + t * 768;
    float gi = Xrow[tid];
    #pragma unroll
    for (int r = 0; r < 16; ++r) gi = fmaf(s_attn[r], rf_own[r], gi);
    #pragma unroll
    for (int c = 0; c < 6; ++c) gi = fmaf(s_tcw[c], ci_own[c], gi);

    float g0 = bhh_own, g1 = 0.f, g2 = 0.f, g3 = 0.f;
    float gn0 = 0.f, gn1 = 0.f;
    const uint4* hp4 = (const uint4*)s_hp;
    if (hf == 0) {
      #pragma unroll
      for (int i = 0; i < 16; ++i) {
        uint4 h4 = hp4[i];
        g0  = fdot2(wA[4 * i + 0], h4.x, g0);
        g1  = fdot2(wA[4 * i + 1], h4.y, g1);
        g2  = fdot2(wA[4 * i + 2], h4.z, g2);
        g3  = fdot2(wA[4 * i + 3], h4.w, g3);
        gn0 = fdot2(wN[4 * i + 0], h4.x, gn0);
        gn1 = fdot2(wN[4 * i + 1], h4.y, gn1);
        gn0 = fdot2(wN[4 * i + 2], h4.z, gn0);
        gn1 = fdot2(wN[4 * i + 3], h4.w, gn1);
      }
      #pragma unroll
      for (int i = 16; i < 32; ++i) {
        uint4 h4 = hp4[i];
        g0 = fdot2(wA[4 * i + 0], h4.x, g0);
        g1 = fdot2(wA[4 * i + 1], h4.y, g1);
        g2 = fdot2(wA[4 * i + 2], h4.z, g2);
        g3 = fdot2(wA[4 * i + 3], h4.w, g3);
      }
    } else {
      #pragma unroll
      for (int i = 0; i < 16; ++i) {
        uint4 h4 = hp4[i];
        g0 = fdot2(wA[4 * i + 0], h4.x, g0);
        g1 = fdot2(wA[4 * i + 1], h4.y, g1);
        g2 = fdot2(wA[4 * i + 2], h4.z, g2);
        g3 = fdot2(wA[4 * i + 3], h4.w, g3);
      }
      #pragma unroll
      for (int i = 16; i < 32; ++i) {
        uint4 h4 = hp4[i];
        g0  = fdot2(wA[4 * i + 0], h4.x, g0);
        g1  = fdot2(wA[4 * i + 1], h4.y, g1);
        g2  = fdot2(wA[4 * i + 2], h4.z, g2);
        g3  = fdot2(wA[4 * i + 3], h4.w, g3);
        gn0 = fdot2(wN[4 * (i - 16) + 0], h4.x, gn0);
        gn1 = fdot2(wN[4 * (i - 16) + 1], h4.y, gn1);
        gn0 = fdot2(wN[4 * (i - 16) + 2], h4.z, gn0);
        gn1 = fdot2(wN[4 * (i - 16) + 3], h4.w, gn1);
      }
    }
    const float gh = (g0 + g1) + (g2 + g3);
    const float ghn = gn0 + gn1;
    const float pre = gi + gh;

    float rg = 0.f;
    if (tid < 256) {
      rg = 1.f / (1.f + __expf(-pre));  // reset gate (kept in register)
      // n-column input part (column 512+tid)
      float gin = Xrow[512 + tid];
      const float4* rf4 = (const float4*)(s_rfnT + tid * 20);
      #pragma unroll
      for (int k = 0; k < 4; ++k) {
        float4 v = rf4[k];
        gin = fmaf(s_attn[4 * k + 0], v.x, gin);
        gin = fmaf(s_attn[4 * k + 1], v.y, gin);
        gin = fmaf(s_attn[4 * k + 2], v.z, gin);
        gin = fmaf(s_attn[4 * k + 3], v.w, gin);
      }
      const float4* ci4 = (const float4*)(s_cinT + tid * 12);
      float4 c0 = ci4[0], c1 = ci4[1];
      gin = fmaf(s_tcw[0], c0.x, gin); gin = fmaf(s_tcw[1], c0.y, gin);
      gin = fmaf(s_tcw[2], c0.z, gin); gin = fmaf(s_tcw[3], c0.w, gin);
      gin = fmaf(s_tcw[4], c1.x, gin); gin = fmaf(s_tcw[5], c1.y, gin);
      s_gin[tid] = gin;
      s_pn[tid] = ghn;
    } else {
      s_z[tid - 256] = 1.f / (1.f + __expf(-pre));  // update gate
      s_pn[tid] = ghn;
    }
    __syncthreads();
    // ---- phase 4: combine gates, update h ----
    if (tid < 256) {
      const float hn_h = s_pn[tid] + s_pn[tid + 256] + s_bhh[512 + tid];
      const float n = tanhf(s_gin[tid] + rg * hn_h);
      const float z = s_z[tid];
      const float hnew = (1.f - z) * n + z * s_h[tid];
      s_h[tid] = hnew;
      const ushort h16 = f2h(hnew);
      ((ushort*)s_hp)[tid] = h16;
      Ah[((size_t)(b * 128 + t)) * 256 + tid] = h16;
    }
    __syncthreads();
  }
}

// ---------------------------------------------------------------------------
// Logits: out[4096,32000] = Ah[4096,256](fp16) @ Bt[32000,256](fp16)^T + bout
// 128x128 tile, BK=64, 4 waves x (64x64), mfma_f32_16x16x32_f16.
// K-loop rotated: global loads for tile kt+1 issued before MFMA of tile kt
// (T14 issue-early), so L2/HBM latency hides under the MFMA cluster.
// ---------------------------------------------------------------------------
__global__ __launch_bounds__(256) void k_gemm(
    const ushort* __restrict__ Ahp, const ushort* __restrict__ Btp,
    const float* __restrict__ bout, float* __restrict__ out)
{
  __shared__ __align__(16) ushort As[128 * 64];
  __shared__ __align__(16) ushort Bs[128 * 64];
  const int tid = threadIdx.x;
  const int lane = tid & 63, wid = tid >> 6;
  const int wr = wid >> 1, wc = wid & 1;
  const int m0 = blockIdx.y * 128, n0 = blockIdx.x * 128;

  f32x4v acc[4][4];
  #pragma unroll
  for (int i = 0; i < 4; ++i)
    #pragma unroll
    for (int j = 0; j < 4; ++j) acc[i][j] = (f32x4v){0.f, 0.f, 0.f, 0.f};

  const int srow = tid >> 3, scc = tid & 7;   // 256 threads cover 32 rows x 8 chunks
  uint4 av[4], bv[4];
  #pragma unroll
  for (int p = 0; p < 4; ++p) {
    int row = p * 32 + srow;
    av[p] = *(const uint4*)(Ahp + (size_t)(m0 + row) * 256 + scc * 8);
    bv[p] = *(const uint4*)(Btp + (size_t)(n0 + row) * 256 + scc * 8);
  }

  for (int kt = 0; kt < 4; ++kt) {
    __syncthreads();
    #pragma unroll
    for (int p = 0; p < 4; ++p) {
      int row = p * 32 + srow;
      int byte = (row * 128 + scc * 16) ^ ((row & 7) << 4);
      *(uint4*)((char*)As + byte) = av[p];
      *(uint4*)((char*)Bs + byte) = bv[p];
    }
    __syncthreads();
    if (kt < 3) {
      #pragma unroll
      for (int p = 0; p < 4; ++p) {
        int row = p * 32 + srow;
        av[p] = *(const uint4*)(Ahp + (size_t)(m0 + row) * 256 + (kt + 1) * 64 + scc * 8);
        bv[p] = *(const uint4*)(Btp + (size_t)(n0 + row) * 256 + (kt + 1) * 64 + scc * 8);
      }
    }
    #pragma unroll
    for (int ks = 0; ks < 2; ++ks) {
      f16x8 af[4], bf[4];
      #pragma unroll
      for (int mi = 0; mi < 4; ++mi) {
        int row = wr * 64 + mi * 16 + (lane & 15);
        int byte = (row * 128 + ks * 64 + (lane >> 4) * 16) ^ ((row & 7) << 4);
        af[mi] = *(const f16x8*)((const char*)As + byte);
      }
      #pragma unroll
      for (int ni = 0; ni < 4; ++ni) {
        int row = wc * 64 + ni * 16 + (lane & 15);
        int byte = (row * 128 + ks * 64 + (lane >> 4) * 16) ^ ((row & 7) << 4);
        bf[ni] = *(const f16x8*)((const char*)Bs + byte);
      }
      #pragma unroll
      for (int mi = 0; mi < 4; ++mi)
        #pragma unroll
        for (int ni = 0; ni < 4; ++ni)
          acc[mi][ni] = __builtin_amdgcn_mfma_f32_16x16x32_f16(af[mi], bf[ni], acc[mi][ni], 0, 0, 0);
    }
  }
  // epilogue: C/D layout col=lane&15, row=(lane>>4)*4+reg
  #pragma unroll
  for (int ni = 0; ni < 4; ++ni) {
    const int gcol = n0 + wc * 64 + ni * 16 + (lane & 15);
    const float bz = bout[gcol];
    #pragma unroll
    for (int mi = 0; mi < 4; ++mi) {
      const int grow0 = m0 + wr * 64 + mi * 16 + (lane >> 4) * 4;
      f32x4v v = acc[mi][ni];
      #pragma unroll
      for (int j = 0; j < 4; ++j)
        out[(size_t)(grow0 + j) * 32000 + gcol] = v[j] + bz;
    }
  }
}

// ---------------------------------------------------------------------------
extern "C" void kernel_launch(void* const* d_in, const int* in_sizes, int n_in,
                              void* d_out, int out_size, void* d_ws, size_t ws_size,
                              hipStream_t stream)
{
  (void)in_sizes; (void)n_in; (void)out_size; (void)ws_size;
  const float* RF        = (const float*)d_in[0];
  const int*   tokens    = (const int*)d_in[1];
  const float* tok_emb   = (const float*)d_in[2];
  const float* conc_emb  = (const float*)d_in[3];
  const float* anat_emb  = (const float*)d_in[4];
  const float* reg_prior = (const float*)d_in[5];
  const float* con_prior = (const float*)d_in[6];
  const float* Wr = (const float*)d_in[7];   const float* br = (const float*)d_in[8];
  const float* Wa = (const float*)d_in[9];   const float* ba = (const float*)d_in[10];
  const float* Wc = (const float*)d_in[11];  const float* bc = (const float*)d_in[12];
  const float* Wg = (const float*)d_in[13];  const float* bg = (const float*)d_in[14];
  const float* Wi = (const float*)d_in[15];  const float* bi = (const float*)d_in[16];
  const float* Whg = (const float*)d_in[17]; const float* bhg = (const float*)d_in[18];
  const float* Wih = (const float*)d_in[19]; const float* bih = (const float*)d_in[20];
  const float* Whh = (const float*)d_in[21]; const float* bhh = (const float*)d_in[22];
  const float* Wout = (const float*)d_in[23]; const float* bout = (const float*)d_in[24];
  float* out = (float*)d_out;

  float* w = (float*)d_ws;
  size_t off = 0;
  auto alloc = [&](size_t n) { float* p = w + off; off += (n + 63) & ~(size_t)63; return p; };
  float* r_p    = alloc(512 * 256);
  float* aW0    = alloc(4 * 256);
  float* cW0    = alloc(6 * 256);
  float* a_mid  = alloc(128 * 256);
  float* a_new  = alloc(128 * 256);
  float* aWn    = alloc(128 * 256);
  float* c_mid  = alloc(192 * 256);
  float* c_new  = alloc(192 * 256);
  float* c_p    = alloc(192 * 256);
  float* meanRF = alloc(32 * 256);
  float* h0     = alloc(32 * 256);
  float* Pr     = alloc(512 * 256);
  float* Pc     = alloc(192 * 256);
  float* tr     = alloc(512);
  float* tc     = alloc(192);
  float* RFih   = alloc(512 * 768);
  float* Cih    = alloc(192 * 768);
  float* X      = alloc(4096 * 768);
  unsigned int* Wpk = (unsigned int*)alloc(128 * 768);
  ushort* Ah    = (ushort*)alloc(4096 * 256 / 2);
  ushort* Bt    = (ushort*)alloc(32000 * 256 / 2);

  const int* nog = nullptr;
  const float* nof = nullptr;

  // graph phase
  k_t1<<<32, 256, 0, stream>>>(RF, nog, 512, Wr, 256, 256, br, nof, 1, 0, r_p);
  k_t1<<<1, 256, 0, stream>>>(anat_emb, nog, 4, Wa, 256, 256, ba, nof, 1, 0, aW0);
  k_t1<<<1, 256, 0, stream>>>(conc_emb, nog, 6, Wc, 256, 256, bc, nof, 1, 0, cW0);
  k_graph_ra<<<32, 256, 0, stream>>>(r_p, aW0, RF, reg_prior, a_mid);
  k_t1<<<8, 256, 0, stream>>>(a_mid, nog, 128, Wg, 256, 256, bg, anat_emb, 4, 1, a_new);
  k_t1<<<8, 256, 0, stream>>>(a_new, nog, 128, Wa, 256, 256, ba, nof, 1, 0, aWn);
  k_graph_ac<<<32, 256, 0, stream>>>(aWn, cW0, a_new, con_prior, c_mid);
  k_t1<<<12, 256, 0, stream>>>(c_mid, nog, 192, Wg, 256, 256, bg, conc_emb, 6, 1, c_new);
  k_t1<<<12, 256, 0, stream>>>(c_new, nog, 192, Wc, 256, 256, bc, nof, 1, 0, c_p);
  k_mean<<<32, 256, 0, stream>>>(RF, meanRF);
  k_t1<<<2, 256, 0, stream>>>(meanRF, nog, 32, Wi, 256, 256, bi, nof, 1, 0, h0);
  // decode-invariant precomputes
  k_t2<<<32, 256, 0, stream>>>(r_p, 512, Whg, Pr);
  k_t2<<<12, 256, 0, stream>>>(c_p, 192, Whg, Pc);
  k_tvec<<<704, 64, 0, stream>>>(r_p, c_p, bhg, tr, tc);
  k_t1<<<32, 256, 0, stream>>>(RF, nog, 512, Wih + 256 * 768, 768, 768, nof, nof, 1, 0, RFih);
  k_t1<<<12, 256, 0, stream>>>(c_new, nog, 192, Wih + 512 * 768, 768, 768, nof, nof, 1, 0, Cih);
  k_t1<<<256, 256, 0, stream>>>(tok_emb, tokens, 4096, Wih, 768, 768, bih, nof, 1, 0, X);
  k_packwhh<<<384, 256, 0, stream>>>(Whh, Wpk);
  // sequential recurrence
  k_decode<<<32, 512, 0, stream>>>(RFih, Cih, Pr, Pc, tr, tc, bhh, Wpk, X, h0, Ah);
  // logits projection
  k_packwt<<<dim3(1000, 4), 256, 0, stream>>>(Wout, Bt);
  k_gemm<<<dim3(250, 32), 256, 0, stream>>>(Ah, Bt, bout, out);
}